// Round 1
// baseline (1599.167 us; speedup 1.0000x reference)
//
#include <hip/hip_runtime.h>
#include <hip/hip_bf16.h>

typedef __attribute__((ext_vector_type(8))) short short8;
typedef __attribute__((ext_vector_type(4))) float f32x4;

#define BB 16
#define VV 3
#define NN 512
#define HH 512
#define SS 5
#define TT 32
#define DTDX 0.1f

__device__ __forceinline__ float fast_tanh(float x) {
  float xc = fminf(fmaxf(x, -9.f), 9.f);
  float e = __expf(2.f * xc);
  return (e - 1.f) * __builtin_amdgcn_rcpf(e + 1.f);
}

__device__ __forceinline__ short f2bf(float x) {
  __hip_bfloat16 h = __float2bfloat16(x);
  return __builtin_bit_cast(short, h);
}

// ---------------- init: weight transposes ----------------
// W1T[j][c] fp32 [512][16] (c=15 zero-padded)
// W2T[j][k] bf16 [512][512]
// W3T[j][k] bf16 [16][512]  (rows 5..15 zero)
__global__ void init_transpose(const float* __restrict__ W1,
                               const float* __restrict__ W2,
                               const float* __restrict__ W3,
                               float* __restrict__ W1T,
                               short* __restrict__ W2T,
                               short* __restrict__ W3T) {
  const int blk = blockIdx.x;
  const int tid = threadIdx.x;
  if (blk < 256) {
    __shared__ float tile[32][33];
    const int tj = blk & 15, tk = blk >> 4;
    const int tx = tid & 31, ty = tid >> 5;  // tx 0..31, ty 0..7
#pragma unroll
    for (int i = 0; i < 4; ++i) {
      const int k = tk * 32 + ty + i * 8;
      tile[ty + i * 8][tx] = W2[k * 512 + tj * 32 + tx];
    }
    __syncthreads();
#pragma unroll
    for (int i = 0; i < 4; ++i) {
      const int j = tj * 32 + ty + i * 8;
      const int k = tk * 32 + tx;
      W2T[j * 512 + k] = f2bf(tile[tx][ty + i * 8]);
    }
  } else if (blk == 256) {
    for (int idx = tid; idx < 512 * 16; idx += 256) {
      const int j = idx >> 4, c = idx & 15;
      W1T[idx] = (c < 15) ? W1[c * 512 + j] : 0.f;
    }
  } else {
    for (int idx = tid; idx < 16 * 512; idx += 256) {
      const int j = idx >> 9, k = idx & 511;
      W3T[idx] = f2bf((j < 5) ? W3[k * 5 + j] : 0.f);
    }
  }
}

// ---------------- per-step fused cell ----------------
// Block = (batch b, 32-row chunk n0). Phase A: rebuild u_t on [n0-2, n0+33]
// from u_{t-1} & flux_{t-1} (global, previous launch). Phase B: MLP + softmax
// + flux + outputs for owned rows [n0, n0+32).
template <bool FIRST>
__global__ __launch_bounds__(256, 1) void step_kernel(
    const float* __restrict__ u_prev, const float* __restrict__ flux_prev,
    const float* __restrict__ W1T, const float* __restrict__ b1,
    const short* __restrict__ W2T, const float* __restrict__ b2,
    const short* __restrict__ W3T, const float* __restrict__ b3,
    float* __restrict__ u_out, float* __restrict__ states_out,
    float* __restrict__ flux_out, float* __restrict__ actions_out,
    float* __restrict__ rewards_out) {
  __shared__ float u_lds[VV][40];
  __shared__ __align__(16) short h_lds[32 * 512];  // bf16 bits, XOR-swizzled
  __shared__ float logits_lds[32][16];

  const int tid = threadIdx.x;
  const int blk = blockIdx.x;
  const int b = blk >> 4;
  const int n0 = (blk & 15) << 5;

  // ---- Phase A: state update / load ----
  if (tid < 108) {
    const int v = tid / 36;
    const int i = tid - v * 36;
    const int n = (n0 - 2 + i) & (NN - 1);
    const int base = (b * VV + v) * NN;
    const int gi = base + n;
    float uv;
    if (FIRST) {
      uv = u_prev[gi];
    } else {
      const int nm = (n - 1) & (NN - 1);
      uv = u_prev[gi] - DTDX * (flux_prev[base + n] - flux_prev[base + nm]);
      if (i >= 2 && i < 34) {
        u_out[gi] = uv;
        states_out[gi] = uv;
      }
    }
    u_lds[v][i] = uv;
  }
  __syncthreads();

  // ---- Phase B1: h1 = tanh(feats @ W1 + b1), fp32 VALU, store bf16 -> LDS ----
  {
    const int r = tid >> 3;  // row 0..31
    const int g = tid & 7;   // j-group
    float f[15];
#pragma unroll
    for (int v = 0; v < VV; ++v)
#pragma unroll
      for (int s = 0; s < SS; ++s) f[v * 5 + s] = u_lds[v][r + s];
    const int swz = (r & 7) << 3;
    for (int jb = 0; jb < 8; ++jb) {
      short8 hb;
#pragma unroll
      for (int q = 0; q < 8; ++q) {
        const int j = g * 64 + jb * 8 + q;
        const float4* wr = (const float4*)(W1T + j * 16);
        const float4 w0 = wr[0], w1 = wr[1], w2 = wr[2], w3 = wr[3];
        float a = b1[j];
        a += w0.x * f[0] + w0.y * f[1] + w0.z * f[2] + w0.w * f[3];
        a += w1.x * f[4] + w1.y * f[5] + w1.z * f[6] + w1.w * f[7];
        a += w2.x * f[8] + w2.y * f[9] + w2.z * f[10] + w2.w * f[11];
        a += w3.x * f[12] + w3.y * f[13] + w3.z * f[14];
        hb[q] = f2bf(fast_tanh(a));
      }
      const int ke = g * 64 + jb * 8;
      *(short8*)(&h_lds[r * 512 + (ke ^ swz)]) = hb;
    }
  }
  __syncthreads();

  const int lane = tid & 63;
  const int wv = tid >> 6;
  const int ml = lane & 15;
  const int gg = lane >> 4;
  const int aswz = (ml & 7) << 3;

  // ---- Phase B2: h2 = tanh(h1 @ W2 + b2), bf16 MFMA ----
  f32x4 acc[2][8];
#pragma unroll
  for (int mt = 0; mt < 2; ++mt)
#pragma unroll
    for (int nt = 0; nt < 8; ++nt) acc[mt][nt] = (f32x4){0.f, 0.f, 0.f, 0.f};

  const int colbase = wv * 128;
#pragma unroll 2
  for (int ks = 0; ks < 16; ++ks) {
    const int k = ks * 32 + gg * 8;
    const short8 a0 = *(const short8*)(&h_lds[ml * 512 + (k ^ aswz)]);
    const short8 a1 = *(const short8*)(&h_lds[(16 + ml) * 512 + (k ^ aswz)]);
#pragma unroll
    for (int nt = 0; nt < 8; ++nt) {
      const short8 bb =
          *(const short8*)(W2T + (colbase + nt * 16 + ml) * 512 + k);
      acc[0][nt] = __builtin_amdgcn_mfma_f32_16x16x32_bf16(a0, bb, acc[0][nt], 0, 0, 0);
      acc[1][nt] = __builtin_amdgcn_mfma_f32_16x16x32_bf16(a1, bb, acc[1][nt], 0, 0, 0);
    }
  }
  __syncthreads();  // everyone done reading h1

  // epilogue: tanh(acc + b2) -> h_lds (h2), C-layout: row=(gg*4+r), col=ml
#pragma unroll
  for (int nt = 0; nt < 8; ++nt) {
    const int col = colbase + nt * 16 + ml;
    const float bias = b2[col];
#pragma unroll
    for (int mt = 0; mt < 2; ++mt) {
#pragma unroll
      for (int r = 0; r < 4; ++r) {
        const int row = mt * 16 + gg * 4 + r;
        h_lds[row * 512 + (col ^ ((row & 7) << 3))] =
            f2bf(fast_tanh(acc[mt][nt][r] + bias));
      }
    }
  }
  __syncthreads();

  // ---- Phase B3: logits = h2 @ W3 + b3 (waves 0,1) ----
  if (wv < 2) {
    f32x4 a3 = (f32x4){0.f, 0.f, 0.f, 0.f};
#pragma unroll 4
    for (int ks = 0; ks < 16; ++ks) {
      const int k = ks * 32 + gg * 8;
      const short8 a =
          *(const short8*)(&h_lds[(wv * 16 + ml) * 512 + (k ^ aswz)]);
      const short8 bb = *(const short8*)(W3T + ml * 512 + k);
      a3 = __builtin_amdgcn_mfma_f32_16x16x32_bf16(a, bb, a3, 0, 0, 0);
    }
#pragma unroll
    for (int r = 0; r < 4; ++r) logits_lds[wv * 16 + gg * 4 + r][ml] = a3[r];
  }
  __syncthreads();

  // ---- Phase B4: softmax, reward, flux, outputs ----
  if (tid < 32) {
    const int r = tid;
    const int n = n0 + r;
    float lg[5];
#pragma unroll
    for (int s = 0; s < 5; ++s) lg[s] = logits_lds[r][s] + b3[s];
    const float m =
        fmaxf(fmaxf(fmaxf(lg[0], lg[1]), fmaxf(lg[2], lg[3])), lg[4]);
    float e[5], sum = 0.f;
#pragma unroll
    for (int s = 0; s < 5; ++s) {
      e[s] = __expf(lg[s] - m);
      sum += e[s];
    }
    const float inv = 1.f / sum;
    float w[5], rw = 0.f;
#pragma unroll
    for (int s = 0; s < 5; ++s) {
      w[s] = e[s] * inv;
      rw += w[s] * w[s];
    }
    float* ap = actions_out + ((size_t)b * NN + n) * SS;
#pragma unroll
    for (int s = 0; s < 5; ++s) ap[s] = w[s];
    rewards_out[b * NN + n] = -rw;
#pragma unroll
    for (int v = 0; v < VV; ++v) {
      float fx = 0.f;
#pragma unroll
      for (int s = 0; s < 5; ++s) fx += u_lds[v][r + s] * w[s];
      flux_out[(b * VV + v) * NN + n] = fx;
    }
  }
}

// ---------------- epilogue: u_32 -> states[31] ----------------
__global__ void final_update(const float* __restrict__ u_prev,
                             const float* __restrict__ flux_prev,
                             float* __restrict__ states_out) {
  const int idx = blockIdx.x * 256 + threadIdx.x;
  if (idx < BB * VV * NN) {
    const int n = idx & (NN - 1);
    const int base = idx - n;
    const int nm = (n - 1) & (NN - 1);
    states_out[idx] =
        u_prev[idx] - DTDX * (flux_prev[idx] - flux_prev[base + nm]);
  }
}

extern "C" void kernel_launch(void* const* d_in, const int* in_sizes, int n_in,
                              void* d_out, int out_size, void* d_ws,
                              size_t ws_size, hipStream_t stream) {
  const float* u0 = (const float*)d_in[0];
  const float* W1 = (const float*)d_in[1];
  const float* b1 = (const float*)d_in[2];
  const float* W2 = (const float*)d_in[3];
  const float* b2 = (const float*)d_in[4];
  const float* W3 = (const float*)d_in[5];
  const float* b3 = (const float*)d_in[6];

  float* states = (float*)d_out;                      // [32,16,3,512]
  float* actions = states + (size_t)TT * BB * VV * NN;  // [32,16,512,5]
  float* rewards = actions + (size_t)TT * BB * NN * SS; // [32,16,512]

  char* ws = (char*)d_ws;
  float* ubuf[2] = {(float*)ws, (float*)(ws + 98304)};
  float* fbuf[2] = {(float*)(ws + 2 * 98304), (float*)(ws + 3 * 98304)};
  float* W1T = (float*)(ws + 4 * 98304);
  short* W2T = (short*)(ws + 4 * 98304 + 32768);
  short* W3T = (short*)(ws + 4 * 98304 + 32768 + 524288);

  init_transpose<<<dim3(258), dim3(256), 0, stream>>>(W1, W2, W3, W1T, W2T, W3T);

  for (int t = 0; t < TT; ++t) {
    if (t == 0) {
      step_kernel<true><<<dim3(256), dim3(256), 0, stream>>>(
          u0, (const float*)nullptr, W1T, b1, W2T, b2, W3T, b3,
          (float*)nullptr, (float*)nullptr, fbuf[0], actions, rewards);
    } else {
      const float* up = (t == 1) ? u0 : ubuf[(t - 1) & 1];
      step_kernel<false><<<dim3(256), dim3(256), 0, stream>>>(
          up, fbuf[(t - 1) & 1], W1T, b1, W2T, b2, W3T, b3, ubuf[t & 1],
          states + (size_t)(t - 1) * BB * VV * NN, fbuf[t & 1],
          actions + (size_t)t * BB * NN * SS, rewards + (size_t)t * BB * NN);
    }
  }
  final_update<<<dim3((BB * VV * NN + 255) / 256), dim3(256), 0, stream>>>(
      ubuf[1], fbuf[1], states + (size_t)(TT - 1) * BB * VV * NN);
}

// Round 2
// 1225.505 us; speedup vs baseline: 1.3049x; 1.3049x over previous
//
#include <hip/hip_runtime.h>
#include <hip/hip_bf16.h>

typedef __attribute__((ext_vector_type(8))) short short8;
typedef __attribute__((ext_vector_type(4))) float f32x4;

#define BB 16
#define VV 3
#define NN 512
#define HH 512
#define SS 5
#define TT 32
#define DTDX 0.1f

__device__ __forceinline__ float fast_tanh(float x) {
  float xc = fminf(fmaxf(x, -9.f), 9.f);
  float e = __expf(2.f * xc);
  return (e - 1.f) * __builtin_amdgcn_rcpf(e + 1.f);
}

__device__ __forceinline__ short f2bf(float x) {
  __hip_bfloat16 h = __float2bfloat16(x);
  return __builtin_bit_cast(short, h);
}

// ---------------- init: weight repack ----------------
// W1T[j][c] fp32 [512][16] (c=15 zero-padded)
// W2F: fragment-ordered bf16. frag(ct,ks,lane) at ((ct*16+ks)*64+lane)*8:
//   col = ct*16 + (lane&15), k0 = ks*32 + (lane>>4)*8, elems W2[k0+q][col]
// W3F: same for W3 (single col-tile, cols>=5 zero): frag(ks,lane).
__global__ void init_repack(const float* __restrict__ W1,
                            const float* __restrict__ W2,
                            const float* __restrict__ W3,
                            float* __restrict__ W1T,
                            short* __restrict__ W2F,
                            short* __restrict__ W3F) {
  const int blk = blockIdx.x;
  const int tid = threadIdx.x;
  if (blk < 128) {
    // W2F: 32768 fragments, one per thread
    const int fid = blk * 256 + tid;
    const int lane = fid & 63;
    const int rest = fid >> 6;       // 0..511
    const int ks = rest & 15;
    const int ct = rest >> 4;        // 0..31
    const int col = ct * 16 + (lane & 15);
    const int k0 = ks * 32 + (lane >> 4) * 8;
    short8 v;
#pragma unroll
    for (int q = 0; q < 8; ++q) v[q] = f2bf(W2[(size_t)(k0 + q) * 512 + col]);
    *(short8*)(W2F + (size_t)fid * 8) = v;
  } else if (blk < 132) {
    // W3F: 1024 fragments
    const int fid = (blk - 128) * 256 + tid;
    const int lane = fid & 63;
    const int ks = fid >> 6;  // 0..15
    const int ml = lane & 15;
    const int k0 = ks * 32 + (lane >> 4) * 8;
    short8 v;
#pragma unroll
    for (int q = 0; q < 8; ++q)
      v[q] = f2bf((ml < 5) ? W3[(size_t)(k0 + q) * 5 + ml] : 0.f);
    *(short8*)(W3F + (size_t)fid * 8) = v;
  } else {
    for (int idx = tid; idx < 512 * 16; idx += 256) {
      const int j = idx >> 4, c = idx & 15;
      W1T[idx] = (c < 15) ? W1[c * 512 + j] : 0.f;
    }
  }
}

// ---------------- per-step fused cell ----------------
// Block = (batch b, 32-row chunk n0), 1024 threads = 16 waves.
template <bool FIRST>
__global__ __launch_bounds__(1024, 4) void step_kernel(
    const float* __restrict__ u_prev, const float* __restrict__ flux_prev,
    const float* __restrict__ W1T, const float* __restrict__ b1,
    const short* __restrict__ W2F, const float* __restrict__ b2,
    const short* __restrict__ W3F, const float* __restrict__ b3,
    float* __restrict__ u_out, float* __restrict__ states_out,
    float* __restrict__ flux_out, float* __restrict__ actions_out,
    float* __restrict__ rewards_out) {
  __shared__ float u_lds[VV][40];
  __shared__ __align__(16) short h_lds[32 * 512];  // bf16 bits, XOR-swizzled
  __shared__ float logits_lds[32][16];

  const int tid = threadIdx.x;
  const int blk = blockIdx.x;
  const int b = blk >> 4;
  const int n0 = (blk & 15) << 5;

  // ---- Phase A: state update / load ----
  if (tid < 108) {
    const int v = tid / 36;
    const int i = tid - v * 36;
    const int n = (n0 - 2 + i) & (NN - 1);
    const int base = (b * VV + v) * NN;
    const int gi = base + n;
    float uv;
    if (FIRST) {
      uv = u_prev[gi];
    } else {
      const int nm = (n - 1) & (NN - 1);
      uv = u_prev[gi] - DTDX * (flux_prev[base + n] - flux_prev[base + nm]);
      if (i >= 2 && i < 34) {
        u_out[gi] = uv;
        states_out[gi] = uv;
      }
    }
    u_lds[v][i] = uv;
  }
  __syncthreads();

  // ---- Phase B1: h1 = tanh(feats @ W1 + b1), fp32 VALU, store bf16 -> LDS ----
  {
    const int r = tid >> 5;  // row 0..31
    const int g = tid & 31;  // j-group (16 j's each)
    float f[15];
#pragma unroll
    for (int v = 0; v < VV; ++v)
#pragma unroll
      for (int s = 0; s < SS; ++s) f[v * 5 + s] = u_lds[v][r + s];
    const int swz = (r & 7) << 3;
#pragma unroll
    for (int half = 0; half < 2; ++half) {
      short8 hb;
#pragma unroll
      for (int q = 0; q < 8; ++q) {
        const int j = g * 16 + half * 8 + q;
        const float4* wr = (const float4*)(W1T + j * 16);
        const float4 w0 = wr[0], w1 = wr[1], w2 = wr[2], w3 = wr[3];
        float a = b1[j];
        a += w0.x * f[0] + w0.y * f[1] + w0.z * f[2] + w0.w * f[3];
        a += w1.x * f[4] + w1.y * f[5] + w1.z * f[6] + w1.w * f[7];
        a += w2.x * f[8] + w2.y * f[9] + w2.z * f[10] + w2.w * f[11];
        a += w3.x * f[12] + w3.y * f[13] + w3.z * f[14];
        hb[q] = f2bf(fast_tanh(a));
      }
      const int ke = g * 16 + half * 8;
      *(short8*)(&h_lds[r * 512 + (ke ^ swz)]) = hb;
    }
  }
  __syncthreads();

  const int lane = tid & 63;
  const int wv = tid >> 6;  // 0..15
  const int ml = lane & 15;
  const int gg = lane >> 4;
  const int aswz = (ml & 7) << 3;

  // ---- Phase B2: h2 = tanh(h1 @ W2 + b2), bf16 MFMA, 32 cols/wave ----
  f32x4 acc[2][2];
#pragma unroll
  for (int mt = 0; mt < 2; ++mt)
#pragma unroll
    for (int nt = 0; nt < 2; ++nt) acc[mt][nt] = (f32x4){0.f, 0.f, 0.f, 0.f};

  const short8* B2p = (const short8*)W2F;
  const int ct0 = wv * 2;
#pragma unroll 4
  for (int ks = 0; ks < 16; ++ks) {
    const int k = ks * 32 + gg * 8;
    const short8 a0 = *(const short8*)(&h_lds[ml * 512 + (k ^ aswz)]);
    const short8 a1 = *(const short8*)(&h_lds[(16 + ml) * 512 + (k ^ aswz)]);
    const short8 b0 = B2p[(ct0 * 16 + ks) * 64 + lane];
    const short8 b1v = B2p[((ct0 + 1) * 16 + ks) * 64 + lane];
    acc[0][0] = __builtin_amdgcn_mfma_f32_16x16x32_bf16(a0, b0, acc[0][0], 0, 0, 0);
    acc[1][0] = __builtin_amdgcn_mfma_f32_16x16x32_bf16(a1, b0, acc[1][0], 0, 0, 0);
    acc[0][1] = __builtin_amdgcn_mfma_f32_16x16x32_bf16(a0, b1v, acc[0][1], 0, 0, 0);
    acc[1][1] = __builtin_amdgcn_mfma_f32_16x16x32_bf16(a1, b1v, acc[1][1], 0, 0, 0);
  }
  __syncthreads();  // everyone done reading h1

  // epilogue: tanh(acc + b2) -> h_lds (h2); C-layout row=gg*4+r, col=ml
#pragma unroll
  for (int nt = 0; nt < 2; ++nt) {
    const int col = (ct0 + nt) * 16 + ml;
    const float bias = b2[col];
#pragma unroll
    for (int mt = 0; mt < 2; ++mt) {
#pragma unroll
      for (int r = 0; r < 4; ++r) {
        const int row = mt * 16 + gg * 4 + r;
        h_lds[row * 512 + (col ^ ((row & 7) << 3))] =
            f2bf(fast_tanh(acc[mt][nt][r] + bias));
      }
    }
  }
  __syncthreads();

  // ---- Phase B3: logits = h2 @ W3 + b3 (waves 0,1) ----
  if (wv < 2) {
    f32x4 a3 = (f32x4){0.f, 0.f, 0.f, 0.f};
    const short8* B3p = (const short8*)W3F;
#pragma unroll 4
    for (int ks = 0; ks < 16; ++ks) {
      const int k = ks * 32 + gg * 8;
      const short8 a =
          *(const short8*)(&h_lds[(wv * 16 + ml) * 512 + (k ^ aswz)]);
      const short8 bb = B3p[ks * 64 + lane];
      a3 = __builtin_amdgcn_mfma_f32_16x16x32_bf16(a, bb, a3, 0, 0, 0);
    }
#pragma unroll
    for (int r = 0; r < 4; ++r) logits_lds[wv * 16 + gg * 4 + r][ml] = a3[r];
  }
  __syncthreads();

  // ---- Phase B4: softmax, reward, flux, outputs ----
  if (tid < 32) {
    const int r = tid;
    const int n = n0 + r;
    float lg[5];
#pragma unroll
    for (int s = 0; s < 5; ++s) lg[s] = logits_lds[r][s] + b3[s];
    const float m =
        fmaxf(fmaxf(fmaxf(lg[0], lg[1]), fmaxf(lg[2], lg[3])), lg[4]);
    float e[5], sum = 0.f;
#pragma unroll
    for (int s = 0; s < 5; ++s) {
      e[s] = __expf(lg[s] - m);
      sum += e[s];
    }
    const float inv = 1.f / sum;
    float w[5], rw = 0.f;
#pragma unroll
    for (int s = 0; s < 5; ++s) {
      w[s] = e[s] * inv;
      rw += w[s] * w[s];
    }
    float* ap = actions_out + ((size_t)b * NN + n) * SS;
#pragma unroll
    for (int s = 0; s < 5; ++s) ap[s] = w[s];
    rewards_out[b * NN + n] = -rw;
#pragma unroll
    for (int v = 0; v < VV; ++v) {
      float fx = 0.f;
#pragma unroll
      for (int s = 0; s < 5; ++s) fx += u_lds[v][r + s] * w[s];
      flux_out[(b * VV + v) * NN + n] = fx;
    }
  }
}

// ---------------- epilogue: u_32 -> states[31] ----------------
__global__ void final_update(const float* __restrict__ u_prev,
                             const float* __restrict__ flux_prev,
                             float* __restrict__ states_out) {
  const int idx = blockIdx.x * 256 + threadIdx.x;
  if (idx < BB * VV * NN) {
    const int n = idx & (NN - 1);
    const int base = idx - n;
    const int nm = (n - 1) & (NN - 1);
    states_out[idx] =
        u_prev[idx] - DTDX * (flux_prev[idx] - flux_prev[base + nm]);
  }
}

extern "C" void kernel_launch(void* const* d_in, const int* in_sizes, int n_in,
                              void* d_out, int out_size, void* d_ws,
                              size_t ws_size, hipStream_t stream) {
  const float* u0 = (const float*)d_in[0];
  const float* W1 = (const float*)d_in[1];
  const float* b1 = (const float*)d_in[2];
  const float* W2 = (const float*)d_in[3];
  const float* b2 = (const float*)d_in[4];
  const float* W3 = (const float*)d_in[5];
  const float* b3 = (const float*)d_in[6];

  float* states = (float*)d_out;                        // [32,16,3,512]
  float* actions = states + (size_t)TT * BB * VV * NN;  // [32,16,512,5]
  float* rewards = actions + (size_t)TT * BB * NN * SS; // [32,16,512]

  char* ws = (char*)d_ws;
  float* ubuf[2] = {(float*)ws, (float*)(ws + 98304)};
  float* fbuf[2] = {(float*)(ws + 2 * 98304), (float*)(ws + 3 * 98304)};
  float* W1T = (float*)(ws + 4 * 98304);
  short* W2F = (short*)(ws + 4 * 98304 + 32768);
  short* W3F = (short*)(ws + 4 * 98304 + 32768 + 524288);

  init_repack<<<dim3(133), dim3(256), 0, stream>>>(W1, W2, W3, W1T, W2F, W3F);

  for (int t = 0; t < TT; ++t) {
    if (t == 0) {
      step_kernel<true><<<dim3(256), dim3(1024), 0, stream>>>(
          u0, (const float*)nullptr, W1T, b1, W2F, b2, W3F, b3,
          (float*)nullptr, (float*)nullptr, fbuf[0], actions, rewards);
    } else {
      const float* up = (t == 1) ? u0 : ubuf[(t - 1) & 1];
      step_kernel<false><<<dim3(256), dim3(1024), 0, stream>>>(
          up, fbuf[(t - 1) & 1], W1T, b1, W2F, b2, W3F, b3, ubuf[t & 1],
          states + (size_t)(t - 1) * BB * VV * NN, fbuf[t & 1],
          actions + (size_t)t * BB * NN * SS, rewards + (size_t)t * BB * NN);
    }
  }
  final_update<<<dim3((BB * VV * NN + 255) / 256), dim3(256), 0, stream>>>(
      ubuf[1], fbuf[1], states + (size_t)(TT - 1) * BB * VV * NN);
}